// Round 1
// 532.472 us; speedup vs baseline: 1.0642x; 1.0642x over previous
//
#include <hip/hip_runtime.h>
#include <stdint.h>

// Problem constants (fixed by the reference)
#define B_DIM 4
#define S_DIM 2048
#define DIN   4096
#define DOUT  4096
#define M_TOT (B_DIM * S_DIM)   // 8192

typedef __attribute__((ext_vector_type(8))) short  bf16x8;  // 8 bf16 = 4 VGPRs
typedef __attribute__((ext_vector_type(4))) float  f32x4;   // 4 fp32 acc
typedef __attribute__((ext_vector_type(8))) unsigned short u16x8;
typedef __attribute__((ext_vector_type(4))) float  float4v;

__device__ __forceinline__ unsigned short f2b(float f) {
  // round-to-nearest-even bf16
  union { float f; unsigned int i; } v; v.f = f;
  unsigned int r = v.i + 0x7FFFu + ((v.i >> 16) & 1u);
  return (unsigned short)(r >> 16);
}

// ---------------------------------------------------------------------------
// Kernel 1: wb = bf16( aa * tanh(kk * w) ), fp32 -> bf16  (unchanged, verified)
// ---------------------------------------------------------------------------
__global__ void wb_tanh_kernel(const float4v* __restrict__ w, u16x8* __restrict__ wb,
                               const float* __restrict__ kk,
                               const float* __restrict__ aa, int n8) {
  const float k = kk[0];
  const float a = aa[0];
  int i = blockIdx.x * blockDim.x + threadIdx.x;
  const int stride = gridDim.x * blockDim.x;
  for (; i < n8; i += stride) {
    float4v v0 = w[2 * i];
    float4v v1 = w[2 * i + 1];
    u16x8 o;
#pragma unroll
    for (int j = 0; j < 4; ++j) o[j]     = f2b(a * tanhf(k * v0[j]));
#pragma unroll
    for (int j = 0; j < 4; ++j) o[j + 4] = f2b(a * tanhf(k * v1[j]));
    wb[i] = o;
  }
}

// ---------------------------------------------------------------------------
// Kernel 2: xb = bf16(x)  (unchanged, verified)
// ---------------------------------------------------------------------------
__global__ void x_cvt_kernel(const float4v* __restrict__ x, u16x8* __restrict__ xb, int n8) {
  int i = blockIdx.x * blockDim.x + threadIdx.x;
  const int stride = gridDim.x * blockDim.x;
  for (; i < n8; i += stride) {
    float4v v0 = x[2 * i];
    float4v v1 = x[2 * i + 1];
    u16x8 o;
#pragma unroll
    for (int j = 0; j < 4; ++j) o[j]     = f2b(v0[j]);
#pragma unroll
    for (int j = 0; j < 4; ++j) o[j + 4] = f2b(v1[j]);
    xb[i] = o;
  }
}

// ---------------------------------------------------------------------------
// Kernel 3: 256x256 8-phase GEMM (T1+T2+T3+T4+T5).
//   C[M,N] = Xb[M,K] * Wb[N,K]^T + bias, bf16 in / fp32 out, fp32 acc.
//   512 threads = 8 waves (2 M x 4 N), per-wave 128x64 output (acc[8][4]).
//   BK=64, LDS = 2 buf x (A 256x64 + B 256x64) bf16 = 128 KiB.
//   Staging: global_load_lds w=16, LINEAR dest + inverse-XOR-swizzled global
//   source; ds_read applies the same XOR (involution) -> conflict-free b128.
//   Counted vmcnt(4) at K-tile boundaries only; never 0 in steady state.
// ---------------------------------------------------------------------------
#define BM 256
#define BN 256
#define BK 64
#define NT (DIN / BK)   // 64 K-tiles

__device__ __forceinline__ void glds16(const unsigned short* g, unsigned short* l) {
  __builtin_amdgcn_global_load_lds(
      (const __attribute__((address_space(1))) void*)g,
      (__attribute__((address_space(3))) void*)l,
      16, 0, 0);
}

#define BARX()    __builtin_amdgcn_s_barrier()
#define LGKM0()   asm volatile("s_waitcnt lgkmcnt(0)" ::: "memory")
#define WAITVM4() asm volatile("s_waitcnt vmcnt(4)" ::: "memory")
#define WAITVM0() asm volatile("s_waitcnt vmcnt(0)" ::: "memory")

// LDS frag reads: logical 16B block b of row r lives at LDS block b ^ (r&7).
// For all our reads r&7 == lane&7 (row offsets are multiples of 8/16).
#define RD_A(dst, mi, BUFB)                                                   \
  dst[0] = *(const bf16x8*)(aRd + (BUFB) + (mi) * 2048 + blk0);               \
  dst[1] = *(const bf16x8*)(aRd + (BUFB) + (mi) * 2048 + blk1);

#define RD_B(ni, BUFB)                                                        \
  bfr[ni][0] = *(const bf16x8*)(bRd + (BUFB) + (ni) * 2048 + blk0);           \
  bfr[ni][1] = *(const bf16x8*)(bRd + (BUFB) + (ni) * 2048 + blk1);

// one phase's MFMA cluster: 2 mi x 4 ni x 2 ks = 16 MFMA, setprio-wrapped (T5)
#define MFMA_PH(AF, MB)                                                       \
  __builtin_amdgcn_s_setprio(1);                                              \
  {                                                                           \
    _Pragma("unroll")                                                         \
    for (int ks = 0; ks < 2; ++ks)                                            \
      _Pragma("unroll")                                                       \
      for (int i = 0; i < 2; ++i)                                             \
        _Pragma("unroll")                                                     \
        for (int ni = 0; ni < 4; ++ni)                                        \
          acc[(MB) + i][ni] = __builtin_amdgcn_mfma_f32_16x16x32_bf16(        \
              AF[i][ks], bfr[ni][ks], acc[(MB) + i][ni], 0, 0, 0);            \
  }                                                                           \
  __builtin_amdgcn_s_setprio(0);

// One K-tile = 4 phases. Reads of buf finish by P3 (drained at P3 lgkm+bar),
// so P4 may issue glds overwriting this buf (tile t+2 A-halves) race-free.
// Half-tile issue schedule (per wave, 2 glds each):
//   tile T A-halves @ (T-2).P4, B-halves @ (T-1).P1; boundary wait vmcnt(4)
//   leaves exactly the (t+2) A-halves in flight => tile t+1 fully landed.
#define KTILE(t, BUFB)                                                        \
  {                                                                           \
    /* P1: 12 ds_reads + stage (t+1) B-halves */                              \
    RD_B(0, BUFB); RD_B(1, BUFB); RD_B(2, BUFB); RD_B(3, BUFB);               \
    RD_A(afA[0], 0, BUFB); RD_A(afA[1], 1, BUFB);                             \
    issue_half(((t) + 1) * 4 + 2); issue_half(((t) + 1) * 4 + 3);             \
    BARX(); LGKM0();                                                          \
    MFMA_PH(afA, 0);                                                          \
    BARX();                                                                   \
    /* P2: 8 ds_reads (mi 2,3 for now; mi 4,5 ahead) */                       \
    RD_A(afB[0], 2, BUFB); RD_A(afB[1], 3, BUFB);                             \
    RD_A(afA[0], 4, BUFB); RD_A(afA[1], 5, BUFB);                             \
    BARX(); LGKM0();                                                          \
    MFMA_PH(afB, 2);                                                          \
    BARX();                                                                   \
    /* P3: last 4 ds_reads of this buffer */                                  \
    RD_A(afB[0], 6, BUFB); RD_A(afB[1], 7, BUFB);                             \
    BARX(); LGKM0();                                                          \
    MFMA_PH(afA, 4);                                                          \
    BARX();                                                                   \
    /* P4: no ds_reads; stage (t+2) A-halves into this (now-free) buffer */   \
    issue_half(((t) + 2) * 4 + 0); issue_half(((t) + 2) * 4 + 1);             \
    BARX(); LGKM0();                                                          \
    MFMA_PH(afB, 6);                                                          \
    if ((t) + 2 < NT) { WAITVM4(); } else { WAITVM0(); }                      \
    BARX();                                                                   \
  }

__global__ __launch_bounds__(512, 2)
void gemm256_kernel(const unsigned short* __restrict__ A,    // [M_TOT, DIN] bf16 bits
                    const unsigned short* __restrict__ Bw,   // [DOUT, DIN] bf16 bits
                    const float* __restrict__ bias,          // [DOUT] fp32
                    float* __restrict__ C) {                 // [M_TOT, DOUT] fp32
  __shared__ unsigned short lds[2][2][BM * BK];  // [buf][A/B][256*64] = 128 KiB

  const int tid  = threadIdx.x;
  const int wv   = tid >> 6;     // wave 0..7
  const int lane = tid & 63;
  const int l15  = lane & 15;
  const int quad = lane >> 4;
  const int l7   = lane & 7;
  const int rlan = lane >> 3;

  // T1: XCD-aware swizzle (512 % 8 == 0 -> simple form is bijective).
  // Consecutive swz (same XCD) share the B panel (2 MB, fits one L2).
  const int swz = ((blockIdx.x & 7) << 6) | (blockIdx.x >> 3);
  const int bm  = (swz & 31) << 8;   // 32 m-tiles
  const int bn  = (swz >> 5) << 8;   // 16 n-tiles

  // Per-lane staging source. glds dest is linear (base + lane*16B): lane l
  // covers row (l>>3), block (l&7). Under the XOR swizzle, LDS (row, blk b)
  // must hold global block b ^ (row&7) = (l&7) ^ (l>>3)  (row&7 == l>>3 here).
  const unsigned short* aLane = A  + (size_t)(bm + wv * 16 + rlan) * DIN + ((l7 ^ rlan) << 3);
  const unsigned short* bLane = Bw + (size_t)(bn + wv * 16 + rlan) * DIN + ((l7 ^ rlan) << 3);

  auto issue_half = [&](int idx) {   // idx = tile*4 + {0,1:A-half, 2,3:B-half}
    const int kt = idx >> 2;
    if (kt >= NT) return;
    const int hh  = idx & 3;
    const int mat = hh >> 1;
    const int hr  = hh & 1;
    const unsigned short* g =
        (mat ? bLane : aLane) + (size_t)hr * (128 * DIN) + (size_t)kt * BK;
    unsigned short* l = &lds[kt & 1][mat][hr * (128 * BK) + wv * (16 * BK)];
    glds16(g, l);                       // rows w*16 .. w*16+7
    glds16(g + 8 * DIN, l + 8 * BK);    // rows w*16+8 .. +15
  };

  // Prologue: T0 fully + T1 A-halves (matches steady-state pipeline shape).
  issue_half(0); issue_half(1); issue_half(2); issue_half(3);
  issue_half(4); issue_half(5);

  // Compute-side LDS bases (bytes). Wave reads its own A-half / B-half only.
  const int hA   = wv >> 2;        // A half (row 0-127 / 128-255)
  const int hB   = (wv & 3) >> 1;  // B half
  const int wloc = wv & 1;         // 64-col block within B half
  const char* aRd = (const char*)&lds[0][0][0] + hA * 16384 + l15 * 128;
  const char* bRd = (const char*)&lds[0][1][0] + hB * 16384 + wloc * 8192 + l15 * 128;
  const int blk0 = ((0 + quad) ^ l7) * 16;   // ks=0: logical block quad
  const int blk1 = ((4 + quad) ^ l7) * 16;   // ks=1: logical block 4+quad

  f32x4  acc[8][4] = {};
  bf16x8 bfr[4][2], afA[2][2], afB[2][2];

  WAITVM4();   // T0's 8 loads landed; T1 A-halves (4 loads) stay in flight
  BARX();

#pragma unroll 1
  for (int t = 0; t < NT; t += 2) {
    KTILE(t, 0);
    KTILE(t + 1, 65536);
  }

  // --- epilogue: bias add + fp32 store (C/D map: col=lane&15, row=quad*4+e) ---
  const int wm = (wv >> 2) * 128;
  const int wn = (wv & 3) * 64;
#pragma unroll
  for (int ni = 0; ni < 4; ++ni) {
    const int col = bn + wn + ni * 16 + l15;
    const float bv = bias[col];
#pragma unroll
    for (int mi = 0; mi < 8; ++mi) {
      const int row0 = bm + wm + mi * 16 + quad * 4;
#pragma unroll
      for (int e = 0; e < 4; ++e)
        C[(size_t)(row0 + e) * DOUT + col] = acc[mi][ni][e] + bv;
    }
  }
}

// ---------------------------------------------------------------------------
extern "C" void kernel_launch(void* const* d_in, const int* in_sizes, int n_in,
                              void* d_out, int out_size, void* d_ws, size_t ws_size,
                              hipStream_t stream) {
  // setup_inputs order: x, weight, bias, kk, aa (fp32); OUTPUT fp32
  const float* x    = (const float*)d_in[0];  // [8192, 4096] fp32
  const float* w    = (const float*)d_in[1];  // [4096, 4096] fp32
  const float* bias = (const float*)d_in[2];  // [4096] fp32
  const float* kk   = (const float*)d_in[3];  // [1] fp32
  const float* aa   = (const float*)d_in[4];  // [1] fp32
  float* out = (float*)d_out;                 // [8192, 4096] fp32

  // ws layout: wb bf16 [4096,4096] at 0 (32 MB), xb bf16 [8192,4096] at +32MB
  unsigned short* wb = (unsigned short*)d_ws;
  unsigned short* xb = wb + (size_t)DOUT * DIN;

  wb_tanh_kernel<<<2048, 256, 0, stream>>>(
      (const float4v*)w, (u16x8*)wb, kk, aa, DOUT * DIN / 8);
  x_cvt_kernel<<<4096, 256, 0, stream>>>(
      (const float4v*)x, (u16x8*)xb, M_TOT * DIN / 8);

  // 512 blocks (32 m-tiles x 16 n-tiles), 512 threads, 1 block/CU (128 KiB LDS)
  gemm256_kernel<<<dim3(512), dim3(512), 0, stream>>>(xb, wb, bias, out);
}

// Round 2
// 523.977 us; speedup vs baseline: 1.0814x; 1.0162x over previous
//
#include <hip/hip_runtime.h>
#include <stdint.h>

// Problem constants (fixed by the reference)
#define B_DIM 4
#define S_DIM 2048
#define DIN   4096
#define DOUT  4096
#define M_TOT (B_DIM * S_DIM)   // 8192

typedef __attribute__((ext_vector_type(8))) short  bf16x8;  // 8 bf16 = 4 VGPRs
typedef __attribute__((ext_vector_type(4))) float  f32x4;   // 4 fp32 acc
typedef __attribute__((ext_vector_type(8))) unsigned short u16x8;
typedef __attribute__((ext_vector_type(4))) float  float4v;

__device__ __forceinline__ unsigned short f2b(float f) {
  // round-to-nearest-even bf16
  union { float f; unsigned int i; } v; v.f = f;
  unsigned int r = v.i + 0x7FFFu + ((v.i >> 16) & 1u);
  return (unsigned short)(r >> 16);
}

// ---------------------------------------------------------------------------
// Fused convert kernel (one launch instead of two; inner math byte-identical
// to the previously verified wb_tanh / x_cvt kernels).
//   blocks [0,2048):    wb = bf16( aa * tanh(kk * w) )
//   blocks [2048,6144): xb = bf16(x)
// ---------------------------------------------------------------------------
__global__ void cvt_fused_kernel(const float4v* __restrict__ w, u16x8* __restrict__ wbo,
                                 const float4v* __restrict__ x, u16x8* __restrict__ xbo,
                                 const float* __restrict__ kk,
                                 const float* __restrict__ aa) {
  const int bid = blockIdx.x;
  if (bid < 2048) {
    const float k = kk[0];
    const float a = aa[0];
    const int n8 = DOUT * DIN / 8;             // 2,097,152
    int i = bid * 256 + threadIdx.x;
    for (; i < n8; i += 2048 * 256) {
      float4v v0 = w[2 * i];
      float4v v1 = w[2 * i + 1];
      u16x8 o;
#pragma unroll
      for (int j = 0; j < 4; ++j) o[j]     = f2b(a * tanhf(k * v0[j]));
#pragma unroll
      for (int j = 0; j < 4; ++j) o[j + 4] = f2b(a * tanhf(k * v1[j]));
      wbo[i] = o;
    }
  } else {
    const int n8 = M_TOT * DIN / 8;            // 4,194,304
    int i = (bid - 2048) * 256 + threadIdx.x;
    for (; i < n8; i += 4096 * 256) {
      float4v v0 = x[2 * i];
      float4v v1 = x[2 * i + 1];
      u16x8 o;
#pragma unroll
      for (int j = 0; j < 4; ++j) o[j]     = f2b(v0[j]);
#pragma unroll
      for (int j = 0; j < 4; ++j) o[j + 4] = f2b(v1[j]);
      xbo[i] = o;
    }
  }
}

// ---------------------------------------------------------------------------
// Kernel 3: 256x256 GEMM, 4 ks-major phases per K-tile (rebalanced 8/8/8/0
// ds_reads), unified tile-(t+2) staging at P4 with vmcnt(8), XCD 2D chunking.
//   C[M,N] = Xb[M,K] * Wb[N,K]^T + bias, bf16 in / fp32 out, fp32 acc.
//   512 threads = 8 waves (2 M x 4 N), per-wave 128x64 output (acc[8][4]).
//   LDS layout, XOR swizzle, staging addressing identical to the verified
//   round-1 kernel (bank conflicts measured 0, results passed).
// ---------------------------------------------------------------------------
#define BM 256
#define BN 256
#define BK 64
#define NT (DIN / BK)   // 64 K-tiles

__device__ __forceinline__ void glds16(const unsigned short* g, unsigned short* l) {
  __builtin_amdgcn_global_load_lds(
      (const __attribute__((address_space(1))) void*)g,
      (__attribute__((address_space(3))) void*)l,
      16, 0, 0);
}

#define BARX()    __builtin_amdgcn_s_barrier()
#define LGKM0()   asm volatile("s_waitcnt lgkmcnt(0)" ::: "memory")
#define LGKM4()   asm volatile("s_waitcnt lgkmcnt(4)" ::: "memory")
#define WAITVM8() asm volatile("s_waitcnt vmcnt(8)" ::: "memory")
#define WAITVM0() asm volatile("s_waitcnt vmcnt(0)" ::: "memory")

// B fragments: 4 x ds_read_b128 at one ks (BLK selects ks0/ks1 block set)
#define RDB(dst, BLK, BUFB)                                                   \
  dst[0] = *(const bf16x8*)(bRd + (BUFB) + 0 * 2048 + (BLK));                 \
  dst[1] = *(const bf16x8*)(bRd + (BUFB) + 1 * 2048 + (BLK));                 \
  dst[2] = *(const bf16x8*)(bRd + (BUFB) + 2 * 2048 + (BLK));                 \
  dst[3] = *(const bf16x8*)(bRd + (BUFB) + 3 * 2048 + (BLK));

// A fragments: 4 x ds_read_b128, mi = MB..MB+3 at one ks
#define RDA4(dst, MB, BLK, BUFB)                                              \
  dst[0] = *(const bf16x8*)(aRd + (BUFB) + ((MB) + 0) * 2048 + (BLK));        \
  dst[1] = *(const bf16x8*)(aRd + (BUFB) + ((MB) + 1) * 2048 + (BLK));        \
  dst[2] = *(const bf16x8*)(aRd + (BUFB) + ((MB) + 2) * 2048 + (BLK));        \
  dst[3] = *(const bf16x8*)(aRd + (BUFB) + ((MB) + 3) * 2048 + (BLK));

// one phase's MFMA cluster: 4 mi x 4 ni at one ks = 16 MFMA, setprio-wrapped
#define MFMA_PH(AF, BF, MB)                                                   \
  __builtin_amdgcn_s_setprio(1);                                              \
  {                                                                           \
    _Pragma("unroll")                                                         \
    for (int i = 0; i < 4; ++i)                                               \
      _Pragma("unroll")                                                       \
      for (int ni = 0; ni < 4; ++ni)                                          \
        acc[(MB) + i][ni] = __builtin_amdgcn_mfma_f32_16x16x32_bf16(          \
            AF[i], BF[ni], acc[(MB) + i][ni], 0, 0, 0);                       \
  }                                                                           \
  __builtin_amdgcn_s_setprio(0);

// One K-tile = 4 ks-major phases. All buf-t ds_reads issued by P3 and drained
// by each wave's P3 LGKM0; P3's closing barrier therefore makes P4's staging
// of tile t+2 into this same buffer race-free. Per-element accumulation order
// (ks0 then ks1) matches the verified round-1 kernel exactly.
#define KTILE(t, BUFB)                                                        \
  {                                                                           \
    /* P1: ks0 B (4) + ks0 A mi0-3 (4) */                                     \
    RDB(bfr0, blk0, BUFB);                                                    \
    RDA4(afA, 0, blk0, BUFB);                                                 \
    LGKM4(); BARX(); LGKM0();                                                 \
    MFMA_PH(afA, bfr0, 0);                                                    \
    BARX();                                                                   \
    /* P2: ks0 A mi4-7 (4) + ks1 B (4) */                                     \
    RDA4(afB, 4, blk0, BUFB);                                                 \
    RDB(bfr1, blk1, BUFB);                                                    \
    LGKM4(); BARX(); LGKM0();                                                 \
    MFMA_PH(afB, bfr0, 4);                                                    \
    BARX();                                                                   \
    /* P3: ks1 A mi0-7 (8) — last reads of this buffer */                     \
    RDA4(afA, 0, blk1, BUFB);                                                 \
    RDA4(afB, 4, blk1, BUFB);                                                 \
    LGKM4(); BARX(); LGKM0();                                                 \
    MFMA_PH(afA, bfr1, 0);                                                    \
    BARX();                                                                   \
    /* P4: no reads; stage tile t+2 (A+B, 8 glds) into this now-free buf */   \
    stage((t) + 2);                                                           \
    BARX();                                                                   \
    MFMA_PH(afB, bfr1, 4);                                                    \
    if ((t) + 2 < NT) { WAITVM8(); } else { WAITVM0(); }                      \
    BARX();                                                                   \
  }

__global__ __launch_bounds__(512, 2)
void gemm256_kernel(const unsigned short* __restrict__ A,    // [M_TOT, DIN] bf16 bits
                    const unsigned short* __restrict__ Bw,   // [DOUT, DIN] bf16 bits
                    const float* __restrict__ bias,          // [DOUT] fp32
                    float* __restrict__ C) {                 // [M_TOT, DOUT] fp32
  __shared__ unsigned short lds[2][2][BM * BK];  // [buf][A/B][256*64] = 128 KiB

  const int tid  = threadIdx.x;
  const int wv   = tid >> 6;     // wave 0..7
  const int lane = tid & 63;
  const int l15  = lane & 15;
  const int quad = lane >> 4;
  const int l7   = lane & 7;
  const int rlan = lane >> 3;

  // T1 variant: XCD-aware 2D chunking. Grid 512 = 32 m-tiles x 16 n-tiles;
  // XCD (bid&7) owns an 8x8 tile chunk (A 16 MB + B 16 MB footprint instead
  // of all 64 MB of A under the previous column mapping). Bijective.
  const int xcd = blockIdx.x & 7;
  const int idx = blockIdx.x >> 3;                  // 0..63 within XCD
  const int bm  = ((((xcd & 3) << 3) | (idx & 7)) << 8);
  const int bn  = ((((xcd >> 2) << 3) | (idx >> 3)) << 8);

  // Per-lane staging source (verified round 1: LDS block b of row r holds
  // global block b ^ (r&7); glds dest linear => pre-swizzle the source).
  const unsigned short* aLane = A  + (size_t)(bm + wv * 16 + rlan) * DIN + ((l7 ^ rlan) << 3);
  const unsigned short* bLane = Bw + (size_t)(bn + wv * 16 + rlan) * DIN + ((l7 ^ rlan) << 3);

  auto stage = [&](int kt) {   // full tile: A halves + B halves, 8 glds/wave
    if (kt >= NT) return;
    const int buf = kt & 1;
    const size_t ko = (size_t)kt * BK;
#pragma unroll
    for (int hr = 0; hr < 2; ++hr) {
      const unsigned short* ga = aLane + (size_t)hr * (128 * DIN) + ko;
      unsigned short* la = &lds[buf][0][hr * (128 * BK) + wv * (16 * BK)];
      glds16(ga, la);
      glds16(ga + 8 * DIN, la + 8 * BK);
      const unsigned short* gb = bLane + (size_t)hr * (128 * DIN) + ko;
      unsigned short* lb = &lds[buf][1][hr * (128 * BK) + wv * (16 * BK)];
      glds16(gb, lb);
      glds16(gb + 8 * DIN, lb + 8 * BK);
    }
  };

  // Prologue: tiles 0 and 1 fully staged; wait for tile 0, keep tile 1 in flight.
  stage(0); stage(1);

  // Compute-side LDS bases (bytes). Wave reads its own A-half / B-half only.
  const int hA   = wv >> 2;        // A half (rows 0-127 / 128-255)
  const int hB   = (wv & 3) >> 1;  // B half
  const int wloc = wv & 1;         // 64-col block within B half
  const char* aRd = (const char*)&lds[0][0][0] + hA * 16384 + l15 * 128;
  const char* bRd = (const char*)&lds[0][1][0] + hB * 16384 + wloc * 8192 + l15 * 128;
  const int blk0 = ((0 + quad) ^ l7) * 16;   // ks=0: logical block quad
  const int blk1 = ((4 + quad) ^ l7) * 16;   // ks=1: logical block 4+quad

  f32x4  acc[8][4] = {};
  bf16x8 bfr0[4], bfr1[4], afA[4], afB[4];

  WAITVM8();   // tile 0's 8 loads landed; tile 1's 8 stay in flight
  BARX();

#pragma unroll 1
  for (int t = 0; t < NT; t += 2) {
    KTILE(t, 0);
    KTILE(t + 1, 65536);
  }

  // --- epilogue: bias add + fp32 store (C/D map: col=lane&15, row=quad*4+e) ---
  const int wm = (wv >> 2) * 128;
  const int wn = (wv & 3) * 64;
#pragma unroll
  for (int ni = 0; ni < 4; ++ni) {
    const int col = bn + wn + ni * 16 + l15;
    const float bv = bias[col];
#pragma unroll
    for (int mi = 0; mi < 8; ++mi) {
      const int row0 = bm + wm + mi * 16 + quad * 4;
#pragma unroll
      for (int e = 0; e < 4; ++e)
        C[(size_t)(row0 + e) * DOUT + col] = acc[mi][ni][e] + bv;
    }
  }
}

// ---------------------------------------------------------------------------
extern "C" void kernel_launch(void* const* d_in, const int* in_sizes, int n_in,
                              void* d_out, int out_size, void* d_ws, size_t ws_size,
                              hipStream_t stream) {
  // setup_inputs order: x, weight, bias, kk, aa (fp32); OUTPUT fp32
  const float* x    = (const float*)d_in[0];  // [8192, 4096] fp32
  const float* w    = (const float*)d_in[1];  // [4096, 4096] fp32
  const float* bias = (const float*)d_in[2];  // [4096] fp32
  const float* kk   = (const float*)d_in[3];  // [1] fp32
  const float* aa   = (const float*)d_in[4];  // [1] fp32
  float* out = (float*)d_out;                 // [8192, 4096] fp32

  // ws layout: wb bf16 [4096,4096] at 0 (32 MB), xb bf16 [8192,4096] at +32MB
  unsigned short* wb = (unsigned short*)d_ws;
  unsigned short* xb = wb + (size_t)DOUT * DIN;

  cvt_fused_kernel<<<6144, 256, 0, stream>>>(
      (const float4v*)w, (u16x8*)wb, (const float4v*)x, (u16x8*)xb, kk, aa);

  // 512 blocks (32 m-tiles x 16 n-tiles), 512 threads, 1 block/CU (128 KiB LDS)
  gemm256_kernel<<<dim3(512), dim3(512), 0, stream>>>(xb, wb, bias, out);
}

// Round 3
// 519.760 us; speedup vs baseline: 1.0902x; 1.0081x over previous
//
#include <hip/hip_runtime.h>
#include <stdint.h>

// Problem constants (fixed by the reference)
#define B_DIM 4
#define S_DIM 2048
#define DIN   4096
#define DOUT  4096
#define M_TOT (B_DIM * S_DIM)   // 8192

typedef __attribute__((ext_vector_type(8))) short  bf16x8;  // 8 bf16 = 4 VGPRs
typedef __attribute__((ext_vector_type(4))) float  f32x4;   // 4 fp32 acc
typedef __attribute__((ext_vector_type(4))) unsigned short u16x4;   // 8 B
typedef __attribute__((ext_vector_type(4))) float  float4v;

__device__ __forceinline__ unsigned short f2b(float f) {
  // round-to-nearest-even bf16
  union { float f; unsigned int i; } v; v.f = f;
  unsigned int r = v.i + 0x7FFFu + ((v.i >> 16) & 1u);
  return (unsigned short)(r >> 16);
}

// ---------------------------------------------------------------------------
// Fused convert kernel, v2: canonical coalescing.
//   R2 defect: thread i loaded w[2i],w[2i+1] -> 32B lane stride, half-used
//   transactions (~5x roofline). Now: one float4 per thread per step
//   (consecutive lanes -> consecutive 16B), u16x4 (8B) coalesced stores.
//   blocks [0,2048):    wb = bf16( aa * tanh(kk * w) )
//   blocks [2048,6144): xb = bf16(x)
// ---------------------------------------------------------------------------
__global__ void cvt_fused_kernel(const float4v* __restrict__ w, u16x4* __restrict__ wbo,
                                 const float4v* __restrict__ x, u16x4* __restrict__ xbo,
                                 const float* __restrict__ kk,
                                 const float* __restrict__ aa) {
  const int bid = blockIdx.x;
  if (bid < 2048) {
    const float k = kk[0];
    const float a = aa[0];
    const int n4 = DOUT * DIN / 4;             // 4,194,304
    for (int i = bid * 256 + threadIdx.x; i < n4; i += 2048 * 256) {
      float4v v = w[i];
      u16x4 o;
#pragma unroll
      for (int j = 0; j < 4; ++j) o[j] = f2b(a * tanhf(k * v[j]));
      wbo[i] = o;
    }
  } else {
    const int n4 = M_TOT * DIN / 4;            // 8,388,608
    for (int i = (bid - 2048) * 256 + threadIdx.x; i < n4; i += 4096 * 256) {
      float4v v = x[i];
      u16x4 o;
#pragma unroll
      for (int j = 0; j < 4; ++j) o[j] = f2b(v[j]);
      xbo[i] = o;
    }
  }
}

// ---------------------------------------------------------------------------
// Kernel 3: 256x256 GEMM, 4 ks-major phases per K-tile.
//   R3 changes vs R2 (schedule only; addressing/swizzle verified twice):
//   1. Staging spread: B(t+2) issued at P3, A(t+2) at P4 (4+4 glds instead
//      of 8 bunched at P4) — fine ds_read || glds || MFMA interleave (m196).
//   2. LGKM4 pre-barrier wait removed — enter barrier with reads in flight,
//      lgkmcnt(0) only after (template discipline).
//   Race-freedom: B region of buf[t&1] is fully read by every wave at its
//   P2 LGKM0; P2's closing barrier orders all waves => stage B at P3 safe.
//   A region fully read at P3's LGKM0 + closing barrier => stage A at P4.
//   Boundary wait stays vmcnt(8) (= B(t+2)+A(t+2) in flight).
// ---------------------------------------------------------------------------
#define BM 256
#define BN 256
#define BK 64
#define NT (DIN / BK)   // 64 K-tiles

__device__ __forceinline__ void glds16(const unsigned short* g, unsigned short* l) {
  __builtin_amdgcn_global_load_lds(
      (const __attribute__((address_space(1))) void*)g,
      (__attribute__((address_space(3))) void*)l,
      16, 0, 0);
}

#define BARX()    __builtin_amdgcn_s_barrier()
#define LGKM0()   asm volatile("s_waitcnt lgkmcnt(0)" ::: "memory")
#define WAITVM8() asm volatile("s_waitcnt vmcnt(8)" ::: "memory")
#define WAITVM0() asm volatile("s_waitcnt vmcnt(0)" ::: "memory")

// B fragments: 4 x ds_read_b128 at one ks (BLK selects ks0/ks1 block set)
#define RDB(dst, BLK, BUFB)                                                   \
  dst[0] = *(const bf16x8*)(bRd + (BUFB) + 0 * 2048 + (BLK));                 \
  dst[1] = *(const bf16x8*)(bRd + (BUFB) + 1 * 2048 + (BLK));                 \
  dst[2] = *(const bf16x8*)(bRd + (BUFB) + 2 * 2048 + (BLK));                 \
  dst[3] = *(const bf16x8*)(bRd + (BUFB) + 3 * 2048 + (BLK));

// A fragments: 4 x ds_read_b128, mi = MB..MB+3 at one ks
#define RDA4(dst, MB, BLK, BUFB)                                              \
  dst[0] = *(const bf16x8*)(aRd + (BUFB) + ((MB) + 0) * 2048 + (BLK));        \
  dst[1] = *(const bf16x8*)(aRd + (BUFB) + ((MB) + 1) * 2048 + (BLK));        \
  dst[2] = *(const bf16x8*)(aRd + (BUFB) + ((MB) + 2) * 2048 + (BLK));        \
  dst[3] = *(const bf16x8*)(aRd + (BUFB) + ((MB) + 3) * 2048 + (BLK));

// one phase's MFMA cluster: 4 mi x 4 ni at one ks = 16 MFMA, setprio-wrapped
#define MFMA_PH(AF, BF, MB)                                                   \
  __builtin_amdgcn_s_setprio(1);                                              \
  {                                                                           \
    _Pragma("unroll")                                                         \
    for (int i = 0; i < 4; ++i)                                               \
      _Pragma("unroll")                                                       \
      for (int ni = 0; ni < 4; ++ni)                                          \
        acc[(MB) + i][ni] = __builtin_amdgcn_mfma_f32_16x16x32_bf16(          \
            AF[i], BF[ni], acc[(MB) + i][ni], 0, 0, 0);                       \
  }                                                                           \
  __builtin_amdgcn_s_setprio(0);

#define KTILE(t, BUFB)                                                        \
  {                                                                           \
    /* P1: ks0 B (4) + ks0 A mi0-3 (4) */                                     \
    RDB(bfr0, blk0, BUFB);                                                    \
    RDA4(afA, 0, blk0, BUFB);                                                 \
    BARX(); LGKM0();                                                          \
    MFMA_PH(afA, bfr0, 0);                                                    \
    BARX();                                                                   \
    /* P2: ks0 A mi4-7 (4) + ks1 B (4) — last B reads of this buffer */       \
    RDA4(afB, 4, blk0, BUFB);                                                 \
    RDB(bfr1, blk1, BUFB);                                                    \
    BARX(); LGKM0();                                                          \
    MFMA_PH(afB, bfr0, 4);                                                    \
    BARX();                                                                   \
    /* P3: ks1 A mi0-7 (8, last A reads) + stage B(t+2) into freed B region */\
    RDA4(afA, 0, blk1, BUFB);                                                 \
    RDA4(afB, 4, blk1, BUFB);                                                 \
    stageB((t) + 2);                                                          \
    BARX(); LGKM0();                                                          \
    MFMA_PH(afA, bfr1, 0);                                                    \
    BARX();                                                                   \
    /* P4: no reads; stage A(t+2) into freed A region */                      \
    stageA((t) + 2);                                                          \
    BARX();                                                                   \
    MFMA_PH(afB, bfr1, 4);                                                    \
    if ((t) + 2 < NT) { WAITVM8(); } else { WAITVM0(); }                      \
    BARX();                                                                   \
  }

__global__ __launch_bounds__(512, 2)
void gemm256_kernel(const unsigned short* __restrict__ A,    // [M_TOT, DIN] bf16 bits
                    const unsigned short* __restrict__ Bw,   // [DOUT, DIN] bf16 bits
                    const float* __restrict__ bias,          // [DOUT] fp32
                    float* __restrict__ C) {                 // [M_TOT, DOUT] fp32
  __shared__ unsigned short lds[2][2][BM * BK];  // [buf][A/B][256*64] = 128 KiB

  const int tid  = threadIdx.x;
  const int wv   = tid >> 6;     // wave 0..7
  const int lane = tid & 63;
  const int l15  = lane & 15;
  const int quad = lane >> 4;
  const int l7   = lane & 7;
  const int rlan = lane >> 3;

  // XCD-aware 2D chunking (verified R2: FETCH 540->198 MB). Grid 512 =
  // 32 m-tiles x 16 n-tiles; XCD (bid&7) owns an 8x8 tile chunk. Bijective.
  const int xcd = blockIdx.x & 7;
  const int idx = blockIdx.x >> 3;                  // 0..63 within XCD
  const int bm  = ((((xcd & 3) << 3) | (idx & 7)) << 8);
  const int bn  = ((((xcd >> 2) << 3) | (idx >> 3)) << 8);

  // Per-lane staging source (verified: LDS block b of row r holds global
  // block b ^ (r&7); glds dest linear => pre-swizzle the source).
  const unsigned short* aLane = A  + (size_t)(bm + wv * 16 + rlan) * DIN + ((l7 ^ rlan) << 3);
  const unsigned short* bLane = Bw + (size_t)(bn + wv * 16 + rlan) * DIN + ((l7 ^ rlan) << 3);

  auto stageA = [&](int kt) {   // A halves: 4 glds/wave
    if (kt >= NT) return;
    const int buf = kt & 1;
    const size_t ko = (size_t)kt * BK;
#pragma unroll
    for (int hr = 0; hr < 2; ++hr) {
      const unsigned short* ga = aLane + (size_t)hr * (128 * DIN) + ko;
      unsigned short* la = &lds[buf][0][hr * (128 * BK) + wv * (16 * BK)];
      glds16(ga, la);
      glds16(ga + 8 * DIN, la + 8 * BK);
    }
  };
  auto stageB = [&](int kt) {   // B halves: 4 glds/wave
    if (kt >= NT) return;
    const int buf = kt & 1;
    const size_t ko = (size_t)kt * BK;
#pragma unroll
    for (int hr = 0; hr < 2; ++hr) {
      const unsigned short* gb = bLane + (size_t)hr * (128 * DIN) + ko;
      unsigned short* lb = &lds[buf][1][hr * (128 * BK) + wv * (16 * BK)];
      glds16(gb, lb);
      glds16(gb + 8 * DIN, lb + 8 * BK);
    }
  };

  // Prologue: tiles 0 and 1 fully staged; wait tile 0, keep tile 1 in flight.
  stageB(0); stageA(0); stageB(1); stageA(1);

  // Compute-side LDS bases (bytes). Wave reads its own A-half / B-half only.
  const int hA   = wv >> 2;        // A half (rows 0-127 / 128-255)
  const int hB   = (wv & 3) >> 1;  // B half
  const int wloc = wv & 1;         // 64-col block within B half
  const char* aRd = (const char*)&lds[0][0][0] + hA * 16384 + l15 * 128;
  const char* bRd = (const char*)&lds[0][1][0] + hB * 16384 + wloc * 8192 + l15 * 128;
  const int blk0 = ((0 + quad) ^ l7) * 16;   // ks=0: logical block quad
  const int blk1 = ((4 + quad) ^ l7) * 16;   // ks=1: logical block 4+quad

  f32x4  acc[8][4] = {};
  bf16x8 bfr0[4], bfr1[4], afA[4], afB[4];

  WAITVM8();   // tile 0's 8 loads landed; tile 1's 8 stay in flight
  BARX();

#pragma unroll 1
  for (int t = 0; t < NT; t += 2) {
    KTILE(t, 0);
    KTILE(t + 1, 65536);
  }

  // --- epilogue: bias add + fp32 store (C/D map: col=lane&15, row=quad*4+e) ---
  const int wm = (wv >> 2) * 128;
  const int wn = (wv & 3) * 64;
#pragma unroll
  for (int ni = 0; ni < 4; ++ni) {
    const int col = bn + wn + ni * 16 + l15;
    const float bv = bias[col];
#pragma unroll
    for (int mi = 0; mi < 8; ++mi) {
      const int row0 = bm + wm + mi * 16 + quad * 4;
#pragma unroll
      for (int e = 0; e < 4; ++e)
        C[(size_t)(row0 + e) * DOUT + col] = acc[mi][ni][e] + bv;
    }
  }
}

// ---------------------------------------------------------------------------
extern "C" void kernel_launch(void* const* d_in, const int* in_sizes, int n_in,
                              void* d_out, int out_size, void* d_ws, size_t ws_size,
                              hipStream_t stream) {
  // setup_inputs order: x, weight, bias, kk, aa (fp32); OUTPUT fp32
  const float* x    = (const float*)d_in[0];  // [8192, 4096] fp32
  const float* w    = (const float*)d_in[1];  // [4096, 4096] fp32
  const float* bias = (const float*)d_in[2];  // [4096] fp32
  const float* kk   = (const float*)d_in[3];  // [1] fp32
  const float* aa   = (const float*)d_in[4];  // [1] fp32
  float* out = (float*)d_out;                 // [8192, 4096] fp32

  // ws layout: wb bf16 [4096,4096] at 0 (32 MB), xb bf16 [8192,4096] at +32MB
  unsigned short* wb = (unsigned short*)d_ws;
  unsigned short* xb = wb + (size_t)DOUT * DIN;

  cvt_fused_kernel<<<6144, 256, 0, stream>>>(
      (const float4v*)w, (u16x4*)wb, (const float4v*)x, (u16x4*)xb, kk, aa);

  // 512 blocks (32 m-tiles x 16 n-tiles), 512 threads, 1 block/CU (128 KiB LDS)
  gemm256_kernel<<<dim3(512), dim3(512), 0, stream>>>(xb, wb, bias, out);
}

// Round 4
// 493.908 us; speedup vs baseline: 1.1472x; 1.0523x over previous
//
#include <hip/hip_runtime.h>
#include <stdint.h>

// Problem constants (fixed by the reference)
#define B_DIM 4
#define S_DIM 2048
#define DIN   4096
#define DOUT  4096
#define M_TOT (B_DIM * S_DIM)   // 8192

typedef __attribute__((ext_vector_type(8))) short  bf16x8;  // 8 bf16 = 4 VGPRs
typedef __attribute__((ext_vector_type(4))) float  f32x4;   // 4 fp32 acc
typedef __attribute__((ext_vector_type(4))) unsigned short u16x4;   // 8 B
typedef __attribute__((ext_vector_type(4))) float  float4v;

__device__ __forceinline__ unsigned short f2b(float f) {
  // round-to-nearest-even bf16
  union { float f; unsigned int i; } v; v.f = f;
  unsigned int r = v.i + 0x7FFFu + ((v.i >> 16) & 1u);
  return (unsigned short)(r >> 16);
}

// ---------------------------------------------------------------------------
// Fused convert kernel (unchanged from R3 — canonical coalescing, verified).
//   blocks [0,2048):    wb = bf16( aa * tanh(kk * w) )
//   blocks [2048,6144): xb = bf16(x)
// ---------------------------------------------------------------------------
__global__ void cvt_fused_kernel(const float4v* __restrict__ w, u16x4* __restrict__ wbo,
                                 const float4v* __restrict__ x, u16x4* __restrict__ xbo,
                                 const float* __restrict__ kk,
                                 const float* __restrict__ aa) {
  const int bid = blockIdx.x;
  if (bid < 2048) {
    const float k = kk[0];
    const float a = aa[0];
    const int n4 = DOUT * DIN / 4;             // 4,194,304
    for (int i = bid * 256 + threadIdx.x; i < n4; i += 2048 * 256) {
      float4v v = w[i];
      u16x4 o;
#pragma unroll
      for (int j = 0; j < 4; ++j) o[j] = f2b(a * tanhf(k * v[j]));
      wbo[i] = o;
    }
  } else {
    const int n4 = M_TOT * DIN / 4;            // 8,388,608
    for (int i = (bid - 2048) * 256 + threadIdx.x; i < n4; i += 4096 * 256) {
      float4v v = x[i];
      u16x4 o;
#pragma unroll
      for (int j = 0; j < 4; ++j) o[j] = f2b(v[j]);
      xbo[i] = o;
    }
  }
}

// ---------------------------------------------------------------------------
// Kernel 3: 256x256 GEMM, 4 ks-major phases/K-tile, EVEN staging cadence.
//   R4 changes vs R3 (issue placement only; reads/MFMA/addressing verified):
//   1. m201/m196 fine interleave: exactly ONE half-tile (2 glds) staged in
//      EVERY phase:  t.P1->(t+1).A0, t.P2->(t+1).A1, t.P3->(t+2).B0,
//      t.P4->(t+2).B1.  (R3 bunched 4+4 at P3/P4 — the m196 anti-pattern.)
//   2. Boundary wait vmcnt(8) -> vmcnt(4): newest-4 in flight at end-of-P4
//      are (t+2).B0/B1, forcing tile t+1 (A and B) fully landed. Tail (t+2
//      >= NT) drains with vmcnt(0).
//   3. P4's opening barrier dropped (no LDS reads in P4; glds hazards are
//      carried by the boundary vmcnt + closing barrier).
//   Race ledger:
//     stage (t+1).A@t.P1/P2 writes buf[(t+1)&1].A: tile t-1's A fully read
//       at (t-1).P3 lgkm0 + closing barrier (2 phases earlier). Safe.
//     stage (t+2).B@t.P3/P4 writes buf[t&1].B: B fully read at t.P2 lgkm0 +
//       closing barrier. Safe.
//     consumption of tile t+1 at (t+1).P1 is preceded by t.P4's vmcnt(4) +
//       barrier, which forces (t+1).A0,A1,B0,B1 landed in every wave. Safe.
// ---------------------------------------------------------------------------
#define BM 256
#define BN 256
#define BK 64
#define NT (DIN / BK)   // 64 K-tiles

__device__ __forceinline__ void glds16(const unsigned short* g, unsigned short* l) {
  __builtin_amdgcn_global_load_lds(
      (const __attribute__((address_space(1))) void*)g,
      (__attribute__((address_space(3))) void*)l,
      16, 0, 0);
}

#define BARX()    __builtin_amdgcn_s_barrier()
#define LGKM0()   asm volatile("s_waitcnt lgkmcnt(0)" ::: "memory")
#define WAITVM4() asm volatile("s_waitcnt vmcnt(4)" ::: "memory")
#define WAITVM0() asm volatile("s_waitcnt vmcnt(0)" ::: "memory")

// B fragments: 4 x ds_read_b128 at one ks (BLK selects ks0/ks1 block set)
#define RDB(dst, BLK, BUFB)                                                   \
  dst[0] = *(const bf16x8*)(bRd + (BUFB) + 0 * 2048 + (BLK));                 \
  dst[1] = *(const bf16x8*)(bRd + (BUFB) + 1 * 2048 + (BLK));                 \
  dst[2] = *(const bf16x8*)(bRd + (BUFB) + 2 * 2048 + (BLK));                 \
  dst[3] = *(const bf16x8*)(bRd + (BUFB) + 3 * 2048 + (BLK));

// A fragments: 4 x ds_read_b128, mi = MB..MB+3 at one ks
#define RDA4(dst, MB, BLK, BUFB)                                              \
  dst[0] = *(const bf16x8*)(aRd + (BUFB) + ((MB) + 0) * 2048 + (BLK));        \
  dst[1] = *(const bf16x8*)(aRd + (BUFB) + ((MB) + 1) * 2048 + (BLK));        \
  dst[2] = *(const bf16x8*)(aRd + (BUFB) + ((MB) + 2) * 2048 + (BLK));        \
  dst[3] = *(const bf16x8*)(aRd + (BUFB) + ((MB) + 3) * 2048 + (BLK));

// one phase's MFMA cluster: 4 mi x 4 ni at one ks = 16 MFMA, setprio-wrapped
#define MFMA_PH(AF, BF, MB)                                                   \
  __builtin_amdgcn_s_setprio(1);                                              \
  {                                                                           \
    _Pragma("unroll")                                                         \
    for (int i = 0; i < 4; ++i)                                               \
      _Pragma("unroll")                                                       \
      for (int ni = 0; ni < 4; ++ni)                                          \
        acc[(MB) + i][ni] = __builtin_amdgcn_mfma_f32_16x16x32_bf16(          \
            AF[i], BF[ni], acc[(MB) + i][ni], 0, 0, 0);                       \
  }                                                                           \
  __builtin_amdgcn_s_setprio(0);

#define KTILE(t, BUFB)                                                        \
  {                                                                           \
    /* P1: ks0 B (4) + ks0 A mi0-3 (4); stage (t+1).A0 */                     \
    RDB(bfr0, blk0, BUFB);                                                    \
    RDA4(afA, 0, blk0, BUFB);                                                 \
    stageAh((t) + 1, 0);                                                      \
    BARX(); LGKM0();                                                          \
    MFMA_PH(afA, bfr0, 0);                                                    \
    BARX();                                                                   \
    /* P2: ks0 A mi4-7 (4) + ks1 B (4, last B reads); stage (t+1).A1 */       \
    RDA4(afB, 4, blk0, BUFB);                                                 \
    RDB(bfr1, blk1, BUFB);                                                    \
    stageAh((t) + 1, 1);                                                      \
    BARX(); LGKM0();                                                          \
    MFMA_PH(afB, bfr0, 4);                                                    \
    BARX();                                                                   \
    /* P3: ks1 A mi0-7 (8, last A reads); stage (t+2).B0 */                   \
    RDA4(afA, 0, blk1, BUFB);                                                 \
    RDA4(afB, 4, blk1, BUFB);                                                 \
    stageBh((t) + 2, 0);                                                      \
    BARX(); LGKM0();                                                          \
    MFMA_PH(afA, bfr1, 0);                                                    \
    BARX();                                                                   \
    /* P4: no LDS reads (no opening barrier); stage (t+2).B1 */               \
    stageBh((t) + 2, 1);                                                      \
    MFMA_PH(afB, bfr1, 4);                                                    \
    if ((t) + 2 < NT) { WAITVM4(); } else { WAITVM0(); }                      \
    BARX();                                                                   \
  }

__global__ __launch_bounds__(512, 2)
void gemm256_kernel(const unsigned short* __restrict__ A,    // [M_TOT, DIN] bf16 bits
                    const unsigned short* __restrict__ Bw,   // [DOUT, DIN] bf16 bits
                    const float* __restrict__ bias,          // [DOUT] fp32
                    float* __restrict__ C) {                 // [M_TOT, DOUT] fp32
  __shared__ unsigned short lds[2][2][BM * BK];  // [buf][A/B][256*64] = 128 KiB

  const int tid  = threadIdx.x;
  const int wv   = tid >> 6;     // wave 0..7
  const int lane = tid & 63;
  const int l15  = lane & 15;
  const int quad = lane >> 4;
  const int l7   = lane & 7;
  const int rlan = lane >> 3;

  // XCD-aware 2D chunking (verified R2: FETCH 540->198 MB). Grid 512 =
  // 32 m-tiles x 16 n-tiles; XCD (bid&7) owns an 8x8 tile chunk. Bijective.
  const int xcd = blockIdx.x & 7;
  const int idx = blockIdx.x >> 3;                  // 0..63 within XCD
  const int bm  = ((((xcd & 3) << 3) | (idx & 7)) << 8);
  const int bn  = ((((xcd >> 2) << 3) | (idx >> 3)) << 8);

  // Per-lane staging source (verified: LDS block b of row r holds global
  // block b ^ (r&7); glds dest linear => pre-swizzle the source).
  const unsigned short* aLane = A  + (size_t)(bm + wv * 16 + rlan) * DIN + ((l7 ^ rlan) << 3);
  const unsigned short* bLane = Bw + (size_t)(bn + wv * 16 + rlan) * DIN + ((l7 ^ rlan) << 3);

  auto stageAh = [&](int kt, int hr) {   // one A half-tile: 2 glds/thread
    if (kt >= NT) return;
    const unsigned short* ga = aLane + (size_t)hr * (128 * DIN) + (size_t)kt * BK;
    unsigned short* la = &lds[kt & 1][0][hr * (128 * BK) + wv * (16 * BK)];
    glds16(ga, la);
    glds16(ga + 8 * DIN, la + 8 * BK);
  };
  auto stageBh = [&](int kt, int hr) {   // one B half-tile: 2 glds/thread
    if (kt >= NT) return;
    const unsigned short* gb = bLane + (size_t)hr * (128 * DIN) + (size_t)kt * BK;
    unsigned short* lb = &lds[kt & 1][1][hr * (128 * BK) + wv * (16 * BK)];
    glds16(gb, lb);
    glds16(gb + 8 * DIN, lb + 8 * BK);
  };

  // Prologue: tile 0 fully + tile 1 B-halves (issue order matters for the
  // vmcnt(4): newest 4 = 1.B0/1.B1, so the wait forces tile 0 landed).
  stageBh(0, 0); stageBh(0, 1); stageAh(0, 0); stageAh(0, 1);
  stageBh(1, 0); stageBh(1, 1);

  // Compute-side LDS bases (bytes). Wave reads its own A-half / B-half only.
  const int hA   = wv >> 2;        // A half (rows 0-127 / 128-255)
  const int hB   = (wv & 3) >> 1;  // B half
  const int wloc = wv & 1;         // 64-col block within B half
  const char* aRd = (const char*)&lds[0][0][0] + hA * 16384 + l15 * 128;
  const char* bRd = (const char*)&lds[0][1][0] + hB * 16384 + wloc * 8192 + l15 * 128;
  const int blk0 = ((0 + quad) ^ l7) * 16;   // ks=0: logical block quad
  const int blk1 = ((4 + quad) ^ l7) * 16;   // ks=1: logical block 4+quad

  f32x4  acc[8][4] = {};
  bf16x8 bfr0[4], bfr1[4], afA[4], afB[4];

  WAITVM4();   // tile 0's 8 loads landed; tile 1's B-halves stay in flight
  BARX();

#pragma unroll 1
  for (int t = 0; t < NT; t += 2) {
    KTILE(t, 0);
    KTILE(t + 1, 65536);
  }

  // --- epilogue: bias add + fp32 store (C/D map: col=lane&15, row=quad*4+e) ---
  const int wm = (wv >> 2) * 128;
  const int wn = (wv & 3) * 64;
#pragma unroll
  for (int ni = 0; ni < 4; ++ni) {
    const int col = bn + wn + ni * 16 + l15;
    const float bv = bias[col];
#pragma unroll
    for (int mi = 0; mi < 8; ++mi) {
      const int row0 = bm + wm + mi * 16 + quad * 4;
#pragma unroll
      for (int e = 0; e < 4; ++e)
        C[(size_t)(row0 + e) * DOUT + col] = acc[mi][ni][e] + bv;
    }
  }
}

// ---------------------------------------------------------------------------
extern "C" void kernel_launch(void* const* d_in, const int* in_sizes, int n_in,
                              void* d_out, int out_size, void* d_ws, size_t ws_size,
                              hipStream_t stream) {
  // setup_inputs order: x, weight, bias, kk, aa (fp32); OUTPUT fp32
  const float* x    = (const float*)d_in[0];  // [8192, 4096] fp32
  const float* w    = (const float*)d_in[1];  // [4096, 4096] fp32
  const float* bias = (const float*)d_in[2];  // [4096] fp32
  const float* kk   = (const float*)d_in[3];  // [1] fp32
  const float* aa   = (const float*)d_in[4];  // [1] fp32
  float* out = (float*)d_out;                 // [8192, 4096] fp32

  // ws layout: wb bf16 [4096,4096] at 0 (32 MB), xb bf16 [8192,4096] at +32MB
  unsigned short* wb = (unsigned short*)d_ws;
  unsigned short* xb = wb + (size_t)DOUT * DIN;

  cvt_fused_kernel<<<6144, 256, 0, stream>>>(
      (const float4v*)w, (u16x4*)wb, (const float4v*)x, (u16x4*)xb, kk, aa);

  // 512 blocks (32 m-tiles x 16 n-tiles), 512 threads, 1 block/CU (128 KiB LDS)
  gemm256_kernel<<<dim3(512), dim3(512), 0, stream>>>(xb, wb, bias, out);
}